// Round 13
// baseline (653.397 us; speedup 1.0000x reference)
//
#include <hip/hip_runtime.h>

// Residual VQ forward: x [B=16, D=256, T=4096] fp32, codebooks [NQ=8, BINS=1024, D=256] fp32.
// d_out = quantized [B,D,T] fp32 ++ codes [NQ,B,T] as float.
// Round 13: T4 counted-vmcnt pipeline on the r10 body. 3x16KB chunk buffers, depth-2
// prefetch, per-chunk {vmcnt(4); s_barrier} (never a full drain in the chunk loop) --
// DMA for chunk k+1 stays in flight ACROSS the barrier. Per-stage pipeline restart
// keeps stage_end's global loads out of the vmcnt counting. fmed3-based top-3 insert.
// Numerics identical to r9/r10: fp16 1-term scoring, packed top-3, DELTA=4, fp64 refine3.

#define BB   16
#define DD   256
#define TT   4096
#define NQ   8
#define BINS 1024
#define DELTA 4.0f              // packed/scaled units (score scale = 16x, quantum <= 1.0)
#define SOFF  8192.0f           // shift making packed scores positive
#define OUTQ ((size_t)BB * DD * TT)

typedef _Float16 half8 __attribute__((ext_vector_type(8)));
typedef float    facc  __attribute__((ext_vector_type(4)));

#define MFMA16(A, B, C) __builtin_amdgcn_mfma_f32_16x16x32_f16((A), (B), (C), 0, 0, 0)

// ---------- pack kernel: fp32 codebook -> pre-swizzled fp16 planes ----------
__global__ __launch_bounds__(256)
void rvq_pack_h16(const float* __restrict__ cb, _Float16* __restrict__ pks) {
    int gid = blockIdx.x * 256 + threadIdx.x;       // (q, bin, s)
    int s   = gid & 7;
    int bin = (gid >> 3) & 1023;
    int q   = gid >> 13;
    const float* src = cb + ((size_t)(q * BINS + bin)) * DD + s * 32;
    int cc    = q * 32 + (bin >> 5);
    int nf    = (bin >> 4) & 1;
    int c     = bin & 15;
    int plane = nf * 8 + s;
    size_t base = (size_t)cc * 8192 + (size_t)plane * 512 + c * 8;   // half units
    #pragma unroll
    for (int g = 0; g < 4; ++g) {
        float4 v0 = *(const float4*)(src + g * 8);
        float4 v1 = *(const float4*)(src + g * 8 + 4);
        float vv[8] = { v0.x, v0.y, v0.z, v0.w, v1.x, v1.y, v1.z, v1.w };
        half8 h8;
        #pragma unroll
        for (int j = 0; j < 8; ++j) h8[j] = (_Float16)vv[j];
        *(half8*)&pks[base + g * 128] = h8;
    }
}

// hoff = SOFF - 8*||e||^2   (packed score = 16*(r.e) + hoff, always positive)
__global__ __launch_bounds__(256)
void rvq_esq_off(const float* __restrict__ cb, float* __restrict__ hoff) {
    int q = blockIdx.x;
    const float* e = cb + (size_t)q * BINS * DD;
    for (int bin = threadIdx.x; bin < BINS; bin += 256) {
        const float4* row = (const float4*)(e + (size_t)bin * DD);
        float s = 0.f;
        #pragma unroll 8
        for (int i = 0; i < DD / 4; ++i) {
            float4 v = row[i];
            s += v.x * v.x + v.y * v.y + v.z * v.z + v.w * v.w;
        }
        hoff[q * BINS + bin] = SOFF - 8.0f * s;
    }
}

// ---------- main MFMA kernel: 512 blocks x 256 thr (4 waves), 128 tokens/block ----------
__global__ __launch_bounds__(256, 2)
void rvq_mfma10_kernel(const float* __restrict__ x, const float* __restrict__ cb,
                       const _Float16* __restrict__ pks, const float* __restrict__ hoff,
                       float* __restrict__ out)
{
    __shared__ alignas(16) _Float16 btile[3][16][512];   // 48 KB: 3 chunk buffers
    __shared__ float esq_lds[BINS];                      // 4 KB: offsets, current stage
    __shared__ unsigned short best_lds[4][32];
    __shared__ unsigned short hist_lds[4][NQ][32];

    const int tid = threadIdx.x;
    const int w   = tid >> 6;
    const int l   = tid & 63;
    const int c   = l & 15;
    const int g   = l >> 4;

    const int blk = blockIdx.x;        // 512 blocks
    const int b   = blk >> 5;          // 32 blocks per batch element
    const int t0  = (blk & 31) * 128;
    const int tw  = t0 + w * 32;

    // wave w stages bytes [w*4K, w*4K+4K) of each 16 KB chunk: 4 gload_lds(16B)/lane
    const char* gsrc0 = (const char*)pks + w * 4096 + (l << 4);

    auto issue_chunk = [&](int k, int bu) {
        const char* src = gsrc0 + (size_t)k * 16384;
        char* dst = (char*)(&btile[bu][0][0]) + w * 4096;
        #pragma unroll
        for (int i = 0; i < 4; ++i) {
            __builtin_amdgcn_global_load_lds(
                (const __attribute__((address_space(1))) unsigned int*)(src + i * 1024),
                (__attribute__((address_space(3))) unsigned int*)(dst + i * 1024),
                16, 0, 0);
        }
    };

    // ---- A init: 16*residual = 16*x, split to fp16 (rh, rl); rl NOT fed to MFMA ----
    half8 rh[2][8], rl[2][8];
    {
        const float* xb = x + (size_t)b * DD * TT;
        #pragma unroll
        for (int s = 0; s < 8; ++s) {
            #pragma unroll
            for (int j = 0; j < 8; ++j) {
                int d = s * 32 + g * 8 + j;
                #pragma unroll
                for (int m = 0; m < 2; ++m) {
                    int t = tw + m * 16 + c;
                    float v = 16.0f * xb[(size_t)d * TT + t];
                    _Float16 h = (_Float16)v;
                    rh[m][s][j] = h;
                    rl[m][s][j] = (_Float16)(v - (float)h);
                }
            }
        }
    }
    // stage offset table for stage 0 (256 threads x 4 floats)
    {
        float4 v = *(const float4*)(hoff + tid * 4);
        *(float4*)&esq_lds[tid * 4] = v;
    }
    __syncthreads();   // esq visible; clean vmcnt state before the counted pipeline

    // packed top-3 fold state: slot (fm, fj) = token fm*16 + 4*g + fj
    float p1[2][4], p2[2][4], p3[2][4];

    auto reset_slots = [&]() {
        #pragma unroll
        for (int m = 0; m < 2; ++m)
            #pragma unroll
            for (int j = 0; j < 4; ++j) { p1[m][j] = 0.f; p2[m][j] = 0.f; p3[m][j] = 0.f; }
    };

    auto compute_chunk = [&](int bu, int ch) {
        facc a00 = {0.f,0.f,0.f,0.f}, a01 = {0.f,0.f,0.f,0.f};
        facc a10 = {0.f,0.f,0.f,0.f}, a11 = {0.f,0.f,0.f,0.f};
        const int roff = g * 128 + c * 8;
        const float q0 = esq_lds[ch * 32 + c];          // ds_read, hidden under MFMA
        const float q1 = esq_lds[ch * 32 + 16 + c];
        const _Float16 (*bt)[512] = btile[bu];

        __builtin_amdgcn_s_setprio(1);
        #pragma unroll
        for (int s = 0; s < 8; ++s) {
            half8 b0 = *(const half8*)&bt[s][roff];
            half8 b1 = *(const half8*)&bt[8 + s][roff];
            a00 = MFMA16(rh[0][s], b0, a00);
            a10 = MFMA16(rh[1][s], b0, a10);
            a01 = MFMA16(rh[0][s], b1, a01);
            a11 = MFMA16(rh[1][s], b1, a11);
        }
        __builtin_amdgcn_s_setprio(0);

        const unsigned idx0 = 1023u - (unsigned)(ch * 32 + c);   // lower bin -> larger tag
        const unsigned idx1 = idx0 - 16u;
        #pragma unroll
        for (int fm = 0; fm < 2; ++fm) {
            #pragma unroll
            for (int fj = 0; fj < 4; ++fj) {
                float s0 = (fm ? a10[fj] : a00[fj]) + q0;
                float s1 = (fm ? a11[fj] : a01[fj]) + q1;
                float v0 = __builtin_bit_cast(float,
                             (__builtin_bit_cast(unsigned, s0) & ~1023u) | idx0);
                float v1 = __builtin_bit_cast(float,
                             (__builtin_bit_cast(unsigned, s1) & ~1023u) | idx1);
                // sorted-insert via med3: p1'=max(p1,v); p2'=med3(v,p1,p2); p3'=med3(v,p2,p3)
                float o1 = p1[fm][fj], o2 = p2[fm][fj], o3 = p3[fm][fj];
                p1[fm][fj] = fmaxf(o1, v0);
                p2[fm][fj] = __builtin_amdgcn_fmed3f(v0, o1, o2);
                p3[fm][fj] = __builtin_amdgcn_fmed3f(v0, o2, o3);
                o1 = p1[fm][fj]; o2 = p2[fm][fj]; o3 = p3[fm][fj];
                p1[fm][fj] = fmaxf(o1, v1);
                p2[fm][fj] = __builtin_amdgcn_fmed3f(v1, o1, o2);
                p3[fm][fj] = __builtin_amdgcn_fmed3f(v1, o2, o3);
            }
        }
    };

    // rare: exact fp32 residual chain + fp64 re-score of the three candidates
    auto refine3 = [&](int tkl, int qq, int c1, int c2, int c3) -> int {
        int t = tw + tkl;
        double pa = 0.0, pb = 0.0, pc = 0.0;
        const float* e1p = cb + (size_t)(qq * BINS + c1) * DD;
        const float* e2p = cb + (size_t)(qq * BINS + c2) * DD;
        const float* e3p = cb + (size_t)(qq * BINS + c3) * DD;
        #pragma unroll
        for (int dd = 0; dd < 4; ++dd) {
            int d = l * 4 + dd;
            float rv = x[((size_t)b * DD + d) * TT + t];
            for (int k = 0; k < qq; ++k) {
                int hb = hist_lds[w][k][tkl];
                rv -= cb[(size_t)(k * BINS + hb) * DD + d];
            }
            float e1v = e1p[d], e2v = e2p[d], e3v = e3p[d];
            pa += (double)e1v * (2.0 * (double)rv - (double)e1v);
            pb += (double)e2v * (2.0 * (double)rv - (double)e2v);
            pc += (double)e3v * (2.0 * (double)rv - (double)e3v);
        }
        #pragma unroll
        for (int mk = 1; mk < 64; mk <<= 1) {
            pa += __shfl_xor(pa, mk);
            pb += __shfl_xor(pb, mk);
            pc += __shfl_xor(pc, mk);
        }
        int wbin = c1; double pw = pa;
        if (pb > pw || (pb == pw && c2 < wbin)) { pw = pb; wbin = c2; }
        if (pc > pw || (pc == pw && c3 < wbin)) { pw = pc; wbin = c3; }
        return wbin;
    };

    auto stage_end = [&](int qq) {
        int  bch[2][4], cn2[2][4], cn3[2][4];
        bool gate[2][4];
        #pragma unroll
        for (int fm = 0; fm < 2; ++fm) {
            #pragma unroll
            for (int fj = 0; fj < 4; ++fj) {
                float a1 = p1[fm][fj], a2 = p2[fm][fj], a3 = p3[fm][fj];
                #pragma unroll
                for (int mk = 1; mk < 16; mk <<= 1) {
                    float b1 = __shfl_xor(a1, mk);
                    float b2 = __shfl_xor(a2, mk);
                    float b3 = __shfl_xor(a3, mk);
                    float lo1 = fminf(a1, b1);
                    float m22 = fmaxf(a2, b2);
                    float r1  = fmaxf(a1, b1);
                    float r2  = fmaxf(lo1, m22);
                    float r3  = fmaxf(fminf(lo1, m22), fmaxf(fminf(a2, b2), fmaxf(a3, b3)));
                    a1 = r1; a2 = r2; a3 = r3;
                }
                bch[fm][fj] = 1023 - (int)(__builtin_bit_cast(unsigned, a1) & 1023u);
                cn2[fm][fj] = 1023 - (int)(__builtin_bit_cast(unsigned, a2) & 1023u);
                cn3[fm][fj] = 1023 - (int)(__builtin_bit_cast(unsigned, a3) & 1023u);
                gate[fm][fj] = (a1 - a2 <= DELTA);
            }
        }
        bool anyg = gate[0][0] | gate[0][1] | gate[0][2] | gate[0][3]
                  | gate[1][0] | gate[1][1] | gate[1][2] | gate[1][3];
        if (__any(anyg)) {
            #pragma unroll
            for (int fm = 0; fm < 2; ++fm) {
                #pragma unroll
                for (int fj = 0; fj < 4; ++fj) {
                    unsigned long long nm = __ballot(gate[fm][fj]);
                    if (nm) {
                        for (int g2 = 0; g2 < 4; ++g2) {
                            if ((nm >> (g2 * 16)) & 1ull) {
                                int c1 = __shfl(bch[fm][fj], g2 * 16);
                                int c2 = __shfl(cn2[fm][fj], g2 * 16);
                                int c3 = __shfl(cn3[fm][fj], g2 * 16);
                                int tkl = fm * 16 + g2 * 4 + fj;
                                int wb = refine3(tkl, qq, c1, c2, c3);
                                if (g == g2) bch[fm][fj] = wb;
                            }
                        }
                    }
                }
            }
        }

        // writes: codes + per-wave best/history
        if (c == 0) {
            #pragma unroll
            for (int fm = 0; fm < 2; ++fm)
                #pragma unroll
                for (int fj = 0; fj < 4; ++fj) {
                    int tkl = fm * 16 + g * 4 + fj;
                    best_lds[w][tkl] = (unsigned short)bch[fm][fj];
                    hist_lds[w][qq][tkl] = (unsigned short)bch[fm][fj];
                    out[OUTQ + ((size_t)qq * BB + b) * TT + tw + tkl] = (float)bch[fm][fj];
                }
        }

        // residual update from EXACT fp32 codebook row: 16r -= 16*e[best], re-split fp16
        #pragma unroll
        for (int m = 0; m < 2; ++m) {
            int bin = best_lds[w][m * 16 + c];
            const float* ep = cb + (size_t)(qq * BINS + bin) * DD + g * 8;
            #pragma unroll
            for (int s = 0; s < 8; ++s) {
                float4 e0 = *(const float4*)(ep + s * 32);
                float4 e1 = *(const float4*)(ep + s * 32 + 4);
                float ev[8] = { e0.x, e0.y, e0.z, e0.w, e1.x, e1.y, e1.z, e1.w };
                #pragma unroll
                for (int j = 0; j < 8; ++j) {
                    float rv = (float)rh[m][s][j] + (float)rl[m][s][j];
                    float nr = rv - 16.0f * ev[j];
                    _Float16 nh = (_Float16)nr;
                    rh[m][s][j] = nh;
                    rl[m][s][j] = (_Float16)(nr - (float)nh);
                }
            }
        }
    };

    // ---- main loop: 8 stages; per-stage counted-vmcnt pipeline over 32 chunks ----
    #pragma unroll 1
    for (int q = 0; q < NQ; ++q) {
        reset_slots();
        const int base = q * 32;
        issue_chunk(base + 0, 0);          // prologue: depth-2 prefetch
        issue_chunk(base + 1, 1);
        #pragma unroll 1
        for (int ch = 0; ch < 32; ++ch) {
            __builtin_amdgcn_sched_barrier(0);
            if (ch < 31) {
                asm volatile("s_waitcnt vmcnt(4)" ::: "memory");   // my quarter of ch done
            } else {
                asm volatile("s_waitcnt vmcnt(0)" ::: "memory");   // drain before stage_end
            }
            __builtin_amdgcn_s_barrier();                          // all quarters published
            __builtin_amdgcn_sched_barrier(0);
            if (ch + 2 < 32) issue_chunk(base + ch + 2, (ch + 2) % 3);
            compute_chunk(ch % 3, ch);
        }
        stage_end(q);
        __syncthreads();          // publish residuals/hist; clean state for next stage
        if (q + 1 < NQ) {
            float4 v = *(const float4*)(hoff + (q + 1) * BINS + tid * 4);
            *(float4*)&esq_lds[tid * 4] = v;
            __syncthreads();      // offsets published before next stage reads them
        }
    }

    // ---- final: quantized = x - residual (m-inner: 128B line back-to-back) ----
    {
        const float* xb = x + (size_t)b * DD * TT;
        float* ob = out + (size_t)b * DD * TT;
        #pragma unroll
        for (int s = 0; s < 8; ++s)
            #pragma unroll
            for (int j = 0; j < 8; ++j) {
                int d = s * 32 + g * 8 + j;
                #pragma unroll
                for (int m = 0; m < 2; ++m) {
                    int t = tw + m * 16 + c;
                    float rv = ((float)rh[m][s][j] + (float)rl[m][s][j]) * 0.0625f;
                    ob[(size_t)d * TT + t] = xb[(size_t)d * TT + t] - rv;
                }
            }
    }
}

// ================= fallback fp32 path (round-2, known-good) =================
#define TOK_PER_BLK 32
#define BIN_CHUNK   128
#define KC          32
#define EPAD        36
#define RPAD        260
#define FDELTA      0.0078125f

#define FUPD2(S, BIN, B1, I1, B2, I2)                                        \
    if ((S) > (B2) || ((S) == (B2) && (BIN) < (I2))) {                      \
        if ((S) > (B1) || ((S) == (B1) && (BIN) < (I1))) {                  \
            B2 = B1; I2 = I1; B1 = (S); I1 = (BIN);                         \
        } else { B2 = (S); I2 = (BIN); }                                    \
    }

__global__ __launch_bounds__(256, 2)
void rvq_esq_kernel(const float* __restrict__ cb, float* __restrict__ esq) {
    int q = blockIdx.x;
    const float* e = cb + (size_t)q * BINS * DD;
    for (int bin = threadIdx.x; bin < BINS; bin += 256) {
        const float4* row = (const float4*)(e + (size_t)bin * DD);
        float s = 0.f;
        #pragma unroll 8
        for (int i = 0; i < DD / 4; ++i) {
            float4 v = row[i];
            s += v.x * v.x + v.y * v.y + v.z * v.z + v.w * v.w;
        }
        esq[q * BINS + bin] = s;
    }
}

__global__ __launch_bounds__(256, 2)
void rvq_main_kernel(const float* __restrict__ x, const float* __restrict__ cb,
                     const float* __restrict__ esq, float* __restrict__ out) {
    __shared__ float r_lds[TOK_PER_BLK][RPAD];
    __shared__ float e_lds[BIN_CHUNK][EPAD];
    __shared__ float red_s[16][2][TOK_PER_BLK];
    __shared__ int   red_i[16][2][TOK_PER_BLK];
    __shared__ int   best_lds2[TOK_PER_BLK];

    const int tid = threadIdx.x;
    const int blk = blockIdx.x;
    const int b   = blk >> 7;
    const int t0  = (blk & 127) * TOK_PER_BLK;

    {
        const int tl = tid & 31;
        const int d0 = (tid >> 5) * 32;
        const float* xp = x + (size_t)b * DD * TT + t0 + tl;
        for (int dd = 0; dd < 32; ++dd) {
            int d = d0 + dd;
            r_lds[tl][d] = xp[(size_t)d * TT];
        }
    }
    __syncthreads();

    const int ty = tid >> 4;
    const int tx = tid & 15;

    for (int q = 0; q < NQ; ++q) {
        const float* eb = cb + (size_t)q * BINS * DD;
        const float* es = esq + q * BINS;
        float b1[2] = {-1e30f, -1e30f}, b2[2] = {-1e30f, -1e30f};
        int   i1[2] = {0x7fffffff, 0x7fffffff}, i2[2] = {0x7fffffff, 0x7fffffff};

        for (int cch = 0; cch < BINS / BIN_CHUNK; ++cch) {
            float acc[2][8];
            #pragma unroll
            for (int i = 0; i < 2; ++i)
                #pragma unroll
                for (int j = 0; j < 8; ++j) acc[i][j] = 0.f;

            for (int kc = 0; kc < DD / KC; ++kc) {
                __syncthreads();
                {
                    const int col  = tid & 7;
                    const int row0 = tid >> 3;
                    const float* src = eb + (size_t)(cch * BIN_CHUNK) * DD + kc * KC;
                    #pragma unroll
                    for (int rr = 0; rr < 4; ++rr) {
                        int row = row0 + rr * 32;
                        float4 v = *(const float4*)(src + (size_t)row * DD + col * 4);
                        *(float4*)&e_lds[row][col * 4] = v;
                    }
                }
                __syncthreads();
                #pragma unroll
                for (int k4 = 0; k4 < KC / 4; ++k4) {
                    float4 r0 = *(const float4*)&r_lds[tx][kc * KC + k4 * 4];
                    float4 r1 = *(const float4*)&r_lds[tx + 16][kc * KC + k4 * 4];
                    #pragma unroll
                    for (int bi = 0; bi < 8; ++bi) {
                        float4 e4 = *(const float4*)&e_lds[ty + 16 * bi][k4 * 4];
                        acc[0][bi] += r0.x * e4.x + r0.y * e4.y + r0.z * e4.z + r0.w * e4.w;
                        acc[1][bi] += r1.x * e4.x + r1.y * e4.y + r1.z * e4.z + r1.w * e4.w;
                    }
                }
            }
            #pragma unroll
            for (int bi = 0; bi < 8; ++bi) {
                int bin = cch * BIN_CHUNK + ty + 16 * bi;
                float half_esq = 0.5f * es[bin];
                float s0 = acc[0][bi] - half_esq;
                float s1v = acc[1][bi] - half_esq;
                FUPD2(s0, bin, b1[0], i1[0], b2[0], i2[0]);
                FUPD2(s1v, bin, b1[1], i1[1], b2[1], i2[1]);
            }
        }

        #pragma unroll
        for (int k = 0; k < 2; ++k) {
            red_s[ty][k][tx]      = k ? b2[0] : b1[0];
            red_i[ty][k][tx]      = k ? i2[0] : i1[0];
            red_s[ty][k][tx + 16] = k ? b2[1] : b1[1];
            red_i[ty][k][tx + 16] = k ? i2[1] : i1[1];
        }
        __syncthreads();

        if (tid < TOK_PER_BLK) {
            float g1 = -1e30f, g2 = -1e30f; int gi1 = 0x7fffffff, gi2 = 0x7fffffff;
            #pragma unroll
            for (int j = 0; j < 16; ++j) {
                #pragma unroll
                for (int k = 0; k < 2; ++k) {
                    float s = red_s[j][k][tid]; int ii = red_i[j][k][tid];
                    FUPD2(s, ii, g1, gi1, g2, gi2);
                }
            }
            int bif;
            if (g1 - g2 <= FDELTA) {
                const float* rrow = r_lds[tid];
                double sc[2]; int id2[2] = { gi1, gi2 };
                for (int cc2 = 0; cc2 < 2; ++cc2) {
                    const float* ep = eb + (size_t)id2[cc2] * DD;
                    double acc2 = 0.0;
                    #pragma unroll 4
                    for (int d = 0; d < DD; ++d) {
                        double ev = (double)ep[d];
                        acc2 += ev * (2.0 * (double)rrow[d] - ev);
                    }
                    sc[cc2] = acc2;
                }
                bif = (sc[0] > sc[1] || (sc[0] == sc[1] && id2[0] < id2[1])) ? id2[0] : id2[1];
            } else {
                bif = gi1;
            }
            best_lds2[tid] = bif;
            out[OUTQ + (size_t)q * (BB * TT) + (size_t)b * TT + t0 + tid] = (float)bif;
        }
        __syncthreads();

        {
            const int tok  = tid >> 3;
            const int part = tid & 7;
            const int bin  = best_lds2[tok];
            const float* ep = eb + (size_t)bin * DD + part * 32;
            float* rp = &r_lds[tok][part * 32];
            #pragma unroll
            for (int dd = 0; dd < 32; ++dd) rp[dd] -= ep[dd];
        }
        __syncthreads();
    }

    {
        const int tl = tid & 31;
        const int d0 = (tid >> 5) * 32;
        const float* xp = x + (size_t)b * DD * TT + t0 + tl;
        float*       op = out + (size_t)b * DD * TT + t0 + tl;
        for (int dd = 0; dd < 32; ++dd) {
            int d = d0 + dd;
            op[(size_t)d * TT] = xp[(size_t)d * TT] - r_lds[tl][d];
        }
    }
}

extern "C" void kernel_launch(void* const* d_in, const int* in_sizes, int n_in,
                              void* d_out, int out_size, void* d_ws, size_t ws_size,
                              hipStream_t stream) {
    const float* x  = (const float*)d_in[0];
    const float* cb = (const float*)d_in[1];
    float* out = (float*)d_out;

    const size_t PKS_BYTES = (size_t)NQ * BINS * DD * 2;       // 4 MB fp16 pre-swizzled
    const size_t NEED = PKS_BYTES + (size_t)NQ * BINS * 4;     // + offset table

    if (ws_size >= NEED) {
        _Float16* pks = (_Float16*)d_ws;
        float* hoff = (float*)((char*)d_ws + PKS_BYTES);
        rvq_pack_h16<<<(NQ * BINS * 8) / 256, 256, 0, stream>>>(cb, pks);
        rvq_esq_off<<<NQ, 256, 0, stream>>>(cb, hoff);
        rvq_mfma10_kernel<<<512, 256, 0, stream>>>(x, cb, pks, hoff, out);
    } else {
        float* esq = (float*)d_ws;
        rvq_esq_kernel<<<NQ, 256, 0, stream>>>(cb, esq);
        rvq_main_kernel<<<(BB * TT) / TOK_PER_BLK, 256, 0, stream>>>(x, cb, esq, out);
    }
}

// Round 15
// 622.894 us; speedup vs baseline: 1.0490x; 1.0490x over previous
//
#include <hip/hip_runtime.h>

// Residual VQ forward: x [B=16, D=256, T=4096] fp32, codebooks [NQ=8, BINS=1024, D=256] fp32.
// d_out = quantized [B,D,T] fp32 ++ codes [NQ,B,T] as float.
// Round 14b: barrier-free B-streaming (r14 with the BB-macro collision fixed: register
// sets renamed Bx/By). Each wave loads B-fragments straight from the pre-swizzled fp16
// codebook into registers (coalesced dwordx4, L2-resident), ping-pong Bx/By, 16-bin
// chunks. NO LDS staging, NO barriers in the chunk loop. esq table in LDS, restaged per
// stage. Numerics identical to r9-r13: fp16 1-term scoring, packed top-3, DELTA=4.0,
// fp64 refine3.

#define BB   16
#define DD   256
#define TT   4096
#define NQ   8
#define BINS 1024
#define DELTA 4.0f              // packed/scaled units (score scale = 16x, quantum <= 1.0)
#define SOFF  8192.0f           // shift making packed scores positive
#define OUTQ ((size_t)BB * DD * TT)

typedef _Float16 half8 __attribute__((ext_vector_type(8)));
typedef float    facc  __attribute__((ext_vector_type(4)));

#define MFMA16(A, B, C) __builtin_amdgcn_mfma_f32_16x16x32_f16((A), (B), (C), 0, 0, 0)

// ---------- pack kernel: fp32 codebook -> pre-swizzled fp16, 8 KB chunks ----------
// Chunk k = q*64 + ch covers bins ch*16..+15 of book q. Chunk = [8 planes][512 halves];
// plane s = k-slice; pos = g*128 + c*8 + j <-> (bin = ch*16 + c, d = s*32 + g*8 + j).
// Lane l of the consumer reads 16B at chunk_base + s*1024 + (l>>4)*256 + (l&15)*16.
__global__ __launch_bounds__(256)
void rvq_pack_h16(const float* __restrict__ cb, _Float16* __restrict__ pks) {
    int gid = blockIdx.x * 256 + threadIdx.x;       // (q, bin, s)
    int s   = gid & 7;
    int bin = (gid >> 3) & 1023;
    int q   = gid >> 13;
    const float* src = cb + ((size_t)(q * BINS + bin)) * DD + s * 32;
    int cc    = q * 64 + (bin >> 4);
    int c     = bin & 15;
    size_t base = (size_t)cc * 4096 + (size_t)s * 512 + c * 8;   // half units
    #pragma unroll
    for (int g = 0; g < 4; ++g) {
        float4 v0 = *(const float4*)(src + g * 8);
        float4 v1 = *(const float4*)(src + g * 8 + 4);
        float vv[8] = { v0.x, v0.y, v0.z, v0.w, v1.x, v1.y, v1.z, v1.w };
        half8 h8;
        #pragma unroll
        for (int j = 0; j < 8; ++j) h8[j] = (_Float16)vv[j];
        *(half8*)&pks[base + g * 128] = h8;
    }
}

// hoff = SOFF - 8*||e||^2   (packed score = 16*(r.e) + hoff, always positive)
__global__ __launch_bounds__(256)
void rvq_esq_off(const float* __restrict__ cb, float* __restrict__ hoff) {
    int q = blockIdx.x;
    const float* e = cb + (size_t)q * BINS * DD;
    for (int bin = threadIdx.x; bin < BINS; bin += 256) {
        const float4* row = (const float4*)(e + (size_t)bin * DD);
        float s = 0.f;
        #pragma unroll 8
        for (int i = 0; i < DD / 4; ++i) {
            float4 v = row[i];
            s += v.x * v.x + v.y * v.y + v.z * v.z + v.w * v.w;
        }
        hoff[q * BINS + bin] = SOFF - 8.0f * s;
    }
}

// ---------- main MFMA kernel: 512 blocks x 256 thr (4 waves), 32 tokens/wave ----------
__global__ __launch_bounds__(256, 2)
void rvq_mfma11_kernel(const float* __restrict__ x, const float* __restrict__ cb,
                       const _Float16* __restrict__ pks, const float* __restrict__ hoff,
                       float* __restrict__ out)
{
    __shared__ float esq_lds[BINS];                      // 4 KB: offsets, current stage
    __shared__ unsigned short best_lds[4][32];
    __shared__ unsigned short hist_lds[4][NQ][32];

    const int tid = threadIdx.x;
    const int w   = tid >> 6;
    const int l   = tid & 63;
    const int c   = l & 15;
    const int g   = l >> 4;

    const int blk = blockIdx.x;        // 512 blocks
    const int b   = blk >> 5;          // 32 blocks per batch element
    const int t0  = (blk & 31) * 128;
    const int tw  = t0 + w * 32;

    // per-lane source base inside each 8 KB chunk
    const char* pkbase = (const char*)pks + ((l >> 4) * 256 + (l & 15) * 16);

    // ---- A init: 16*residual = 16*x, split to fp16 (rh, rl); rl NOT fed to MFMA ----
    half8 rh[2][8], rl[2][8];
    {
        const float* xb = x + (size_t)b * DD * TT;
        #pragma unroll
        for (int s = 0; s < 8; ++s) {
            #pragma unroll
            for (int j = 0; j < 8; ++j) {
                int d = s * 32 + g * 8 + j;
                #pragma unroll
                for (int m = 0; m < 2; ++m) {
                    int t = tw + m * 16 + c;
                    float v = 16.0f * xb[(size_t)d * TT + t];
                    _Float16 h = (_Float16)v;
                    rh[m][s][j] = h;
                    rl[m][s][j] = (_Float16)(v - (float)h);
                }
            }
        }
    }
    // stage offset table for stage 0 (256 threads x 4 floats)
    {
        float4 v = *(const float4*)(hoff + tid * 4);
        *(float4*)&esq_lds[tid * 4] = v;
    }
    __syncthreads();

    // packed top-3 fold state: slot (fm, fj) = token fm*16 + 4*g + fj
    float p1[2][4], p2[2][4], p3[2][4];

    // B-fragment register sets (ping-pong, statically named; no macro-name collision)
    half8 Bx[8], By[8];

#define LOADB(BSET, K) do {                                                  \
    const char* _src = pkbase + (size_t)(K) * 8192;                          \
    _Pragma("unroll")                                                        \
    for (int _s = 0; _s < 8; ++_s)                                           \
        BSET[_s] = *(const half8*)(_src + _s * 1024);                        \
} while (0)

#define COMPUTE(BSET, CH) do {                                               \
    facc _a0 = {0.f,0.f,0.f,0.f}, _a1 = {0.f,0.f,0.f,0.f};                   \
    _Pragma("unroll")                                                        \
    for (int _s = 0; _s < 8; ++_s) {                                         \
        _a0 = MFMA16(rh[0][_s], BSET[_s], _a0);                              \
        _a1 = MFMA16(rh[1][_s], BSET[_s], _a1);                              \
    }                                                                        \
    const float _q0 = esq_lds[(CH) * 16 + c];                                \
    const unsigned _idx0 = 1023u - (unsigned)((CH) * 16 + c);                \
    _Pragma("unroll")                                                        \
    for (int _fm = 0; _fm < 2; ++_fm) {                                      \
        _Pragma("unroll")                                                    \
        for (int _fj = 0; _fj < 4; ++_fj) {                                  \
            float _sv = (_fm ? _a1[_fj] : _a0[_fj]) + _q0;                   \
            float _v = __builtin_bit_cast(float,                            \
                         (__builtin_bit_cast(unsigned, _sv) & ~1023u) | _idx0); \
            float _o1 = p1[_fm][_fj], _o2 = p2[_fm][_fj], _o3 = p3[_fm][_fj]; \
            p1[_fm][_fj] = fmaxf(_o1, _v);                                   \
            p2[_fm][_fj] = __builtin_amdgcn_fmed3f(_v, _o1, _o2);            \
            p3[_fm][_fj] = __builtin_amdgcn_fmed3f(_v, _o2, _o3);            \
        }                                                                    \
    }                                                                        \
} while (0)

    // rare: exact fp32 residual chain + fp64 re-score of the three candidates
    auto refine3 = [&](int tkl, int qq, int c1, int c2, int c3) -> int {
        int t = tw + tkl;
        double pa = 0.0, pb = 0.0, pc = 0.0;
        const float* e1p = cb + (size_t)(qq * BINS + c1) * DD;
        const float* e2p = cb + (size_t)(qq * BINS + c2) * DD;
        const float* e3p = cb + (size_t)(qq * BINS + c3) * DD;
        #pragma unroll
        for (int dd = 0; dd < 4; ++dd) {
            int d = l * 4 + dd;
            float rv = x[((size_t)b * DD + d) * TT + t];
            for (int k = 0; k < qq; ++k) {
                int hb = hist_lds[w][k][tkl];
                rv -= cb[(size_t)(k * BINS + hb) * DD + d];
            }
            float e1v = e1p[d], e2v = e2p[d], e3v = e3p[d];
            pa += (double)e1v * (2.0 * (double)rv - (double)e1v);
            pb += (double)e2v * (2.0 * (double)rv - (double)e2v);
            pc += (double)e3v * (2.0 * (double)rv - (double)e3v);
        }
        #pragma unroll
        for (int mk = 1; mk < 64; mk <<= 1) {
            pa += __shfl_xor(pa, mk);
            pb += __shfl_xor(pb, mk);
            pc += __shfl_xor(pc, mk);
        }
        int wbin = c1; double pw = pa;
        if (pb > pw || (pb == pw && c2 < wbin)) { pw = pb; wbin = c2; }
        if (pc > pw || (pc == pw && c3 < wbin)) { pw = pc; wbin = c3; }
        return wbin;
    };

    auto stage_end = [&](int qq) {
        int  bch[2][4], cn2[2][4], cn3[2][4];
        bool gate[2][4];
        #pragma unroll
        for (int fm = 0; fm < 2; ++fm) {
            #pragma unroll
            for (int fj = 0; fj < 4; ++fj) {
                float a1 = p1[fm][fj], a2 = p2[fm][fj], a3 = p3[fm][fj];
                #pragma unroll
                for (int mk = 1; mk < 16; mk <<= 1) {
                    float b1 = __shfl_xor(a1, mk);
                    float b2 = __shfl_xor(a2, mk);
                    float b3 = __shfl_xor(a3, mk);
                    float lo1 = fminf(a1, b1);
                    float m22 = fmaxf(a2, b2);
                    float r1  = fmaxf(a1, b1);
                    float r2  = fmaxf(lo1, m22);
                    float r3  = fmaxf(fminf(lo1, m22), fmaxf(fminf(a2, b2), fmaxf(a3, b3)));
                    a1 = r1; a2 = r2; a3 = r3;
                }
                bch[fm][fj] = 1023 - (int)(__builtin_bit_cast(unsigned, a1) & 1023u);
                cn2[fm][fj] = 1023 - (int)(__builtin_bit_cast(unsigned, a2) & 1023u);
                cn3[fm][fj] = 1023 - (int)(__builtin_bit_cast(unsigned, a3) & 1023u);
                gate[fm][fj] = (a1 - a2 <= DELTA);
            }
        }
        bool anyg = gate[0][0] | gate[0][1] | gate[0][2] | gate[0][3]
                  | gate[1][0] | gate[1][1] | gate[1][2] | gate[1][3];
        if (__any(anyg)) {
            #pragma unroll
            for (int fm = 0; fm < 2; ++fm) {
                #pragma unroll
                for (int fj = 0; fj < 4; ++fj) {
                    unsigned long long nm = __ballot(gate[fm][fj]);
                    if (nm) {
                        for (int g2 = 0; g2 < 4; ++g2) {
                            if ((nm >> (g2 * 16)) & 1ull) {
                                int c1 = __shfl(bch[fm][fj], g2 * 16);
                                int c2 = __shfl(cn2[fm][fj], g2 * 16);
                                int c3 = __shfl(cn3[fm][fj], g2 * 16);
                                int tkl = fm * 16 + g2 * 4 + fj;
                                int wb = refine3(tkl, qq, c1, c2, c3);
                                if (g == g2) bch[fm][fj] = wb;
                            }
                        }
                    }
                }
            }
        }

        // writes: codes + per-wave best/history
        if (c == 0) {
            #pragma unroll
            for (int fm = 0; fm < 2; ++fm)
                #pragma unroll
                for (int fj = 0; fj < 4; ++fj) {
                    int tkl = fm * 16 + g * 4 + fj;
                    best_lds[w][tkl] = (unsigned short)bch[fm][fj];
                    hist_lds[w][qq][tkl] = (unsigned short)bch[fm][fj];
                    out[OUTQ + ((size_t)qq * BB + b) * TT + tw + tkl] = (float)bch[fm][fj];
                }
        }

        // residual update from EXACT fp32 codebook row: 16r -= 16*e[best], re-split fp16
        #pragma unroll
        for (int m = 0; m < 2; ++m) {
            int bin = best_lds[w][m * 16 + c];
            const float* ep = cb + (size_t)(qq * BINS + bin) * DD + g * 8;
            #pragma unroll
            for (int s = 0; s < 8; ++s) {
                float4 e0 = *(const float4*)(ep + s * 32);
                float4 e1 = *(const float4*)(ep + s * 32 + 4);
                float ev[8] = { e0.x, e0.y, e0.z, e0.w, e1.x, e1.y, e1.z, e1.w };
                #pragma unroll
                for (int j = 0; j < 8; ++j) {
                    float rv = (float)rh[m][s][j] + (float)rl[m][s][j];
                    float nr = rv - 16.0f * ev[j];
                    _Float16 nh = (_Float16)nr;
                    rh[m][s][j] = nh;
                    rl[m][s][j] = (_Float16)(nr - (float)nh);
                }
            }
        }
    };

    // ---- main loop: 8 stages x 64 chunks (16 bins); wave-private, barrier-free ----
    #pragma unroll 1
    for (int q = 0; q < NQ; ++q) {
        #pragma unroll
        for (int fm = 0; fm < 2; ++fm)
            #pragma unroll
            for (int fj = 0; fj < 4; ++fj) {
                p1[fm][fj] = 0.f; p2[fm][fj] = 0.f; p3[fm][fj] = 0.f;
            }
        const int base = q * 64;
        LOADB(Bx, base + 0);
        #pragma unroll 1
        for (int p = 0; p < 32; ++p) {
            const int ch = 2 * p;
            LOADB(By, base + ch + 1);
            COMPUTE(Bx, ch);
            if (p < 31) LOADB(Bx, base + ch + 2);
            COMPUTE(By, ch + 1);
        }
        stage_end(q);
        __syncthreads();          // all waves done with this stage's esq
        if (q + 1 < NQ) {
            float4 v = *(const float4*)(hoff + (q + 1) * BINS + tid * 4);
            *(float4*)&esq_lds[tid * 4] = v;
        }
        __syncthreads();          // offsets published before next stage reads them
    }

    // ---- final: quantized = x - residual (m-inner: 128B line back-to-back) ----
    {
        const float* xb = x + (size_t)b * DD * TT;
        float* ob = out + (size_t)b * DD * TT;
        #pragma unroll
        for (int s = 0; s < 8; ++s)
            #pragma unroll
            for (int j = 0; j < 8; ++j) {
                int d = s * 32 + g * 8 + j;
                #pragma unroll
                for (int m = 0; m < 2; ++m) {
                    int t = tw + m * 16 + c;
                    float rv = ((float)rh[m][s][j] + (float)rl[m][s][j]) * 0.0625f;
                    ob[(size_t)d * TT + t] = xb[(size_t)d * TT + t] - rv;
                }
            }
    }
}

// ================= fallback fp32 path (round-2, known-good) =================
#define TOK_PER_BLK 32
#define BIN_CHUNK   128
#define KC          32
#define EPAD        36
#define RPAD        260
#define FDELTA      0.0078125f

#define FUPD2(S, BIN, B1, I1, B2, I2)                                        \
    if ((S) > (B2) || ((S) == (B2) && (BIN) < (I2))) {                      \
        if ((S) > (B1) || ((S) == (B1) && (BIN) < (I1))) {                  \
            B2 = B1; I2 = I1; B1 = (S); I1 = (BIN);                         \
        } else { B2 = (S); I2 = (BIN); }                                    \
    }

__global__ __launch_bounds__(256, 2)
void rvq_esq_kernel(const float* __restrict__ cb, float* __restrict__ esq) {
    int q = blockIdx.x;
    const float* e = cb + (size_t)q * BINS * DD;
    for (int bin = threadIdx.x; bin < BINS; bin += 256) {
        const float4* row = (const float4*)(e + (size_t)bin * DD);
        float s = 0.f;
        #pragma unroll 8
        for (int i = 0; i < DD / 4; ++i) {
            float4 v = row[i];
            s += v.x * v.x + v.y * v.y + v.z * v.z + v.w * v.w;
        }
        esq[q * BINS + bin] = s;
    }
}

__global__ __launch_bounds__(256, 2)
void rvq_main_kernel(const float* __restrict__ x, const float* __restrict__ cb,
                     const float* __restrict__ esq, float* __restrict__ out) {
    __shared__ float r_lds[TOK_PER_BLK][RPAD];
    __shared__ float e_lds[BIN_CHUNK][EPAD];
    __shared__ float red_s[16][2][TOK_PER_BLK];
    __shared__ int   red_i[16][2][TOK_PER_BLK];
    __shared__ int   best_lds2[TOK_PER_BLK];

    const int tid = threadIdx.x;
    const int blk = blockIdx.x;
    const int b   = blk >> 7;
    const int t0  = (blk & 127) * TOK_PER_BLK;

    {
        const int tl = tid & 31;
        const int d0 = (tid >> 5) * 32;
        const float* xp = x + (size_t)b * DD * TT + t0 + tl;
        for (int dd = 0; dd < 32; ++dd) {
            int d = d0 + dd;
            r_lds[tl][d] = xp[(size_t)d * TT];
        }
    }
    __syncthreads();

    const int ty = tid >> 4;
    const int tx = tid & 15;

    for (int q = 0; q < NQ; ++q) {
        const float* eb = cb + (size_t)q * BINS * DD;
        const float* es = esq + q * BINS;
        float b1[2] = {-1e30f, -1e30f}, b2[2] = {-1e30f, -1e30f};
        int   i1[2] = {0x7fffffff, 0x7fffffff}, i2[2] = {0x7fffffff, 0x7fffffff};

        for (int cch = 0; cch < BINS / BIN_CHUNK; ++cch) {
            float acc[2][8];
            #pragma unroll
            for (int i = 0; i < 2; ++i)
                #pragma unroll
                for (int j = 0; j < 8; ++j) acc[i][j] = 0.f;

            for (int kc = 0; kc < DD / KC; ++kc) {
                __syncthreads();
                {
                    const int col  = tid & 7;
                    const int row0 = tid >> 3;
                    const float* src = eb + (size_t)(cch * BIN_CHUNK) * DD + kc * KC;
                    #pragma unroll
                    for (int rr = 0; rr < 4; ++rr) {
                        int row = row0 + rr * 32;
                        float4 v = *(const float4*)(src + (size_t)row * DD + col * 4);
                        *(float4*)&e_lds[row][col * 4] = v;
                    }
                }
                __syncthreads();
                #pragma unroll
                for (int k4 = 0; k4 < KC / 4; ++k4) {
                    float4 r0 = *(const float4*)&r_lds[tx][kc * KC + k4 * 4];
                    float4 r1 = *(const float4*)&r_lds[tx + 16][kc * KC + k4 * 4];
                    #pragma unroll
                    for (int bi = 0; bi < 8; ++bi) {
                        float4 e4 = *(const float4*)&e_lds[ty + 16 * bi][k4 * 4];
                        acc[0][bi] += r0.x * e4.x + r0.y * e4.y + r0.z * e4.z + r0.w * e4.w;
                        acc[1][bi] += r1.x * e4.x + r1.y * e4.y + r1.z * e4.z + r1.w * e4.w;
                    }
                }
            }
            #pragma unroll
            for (int bi = 0; bi < 8; ++bi) {
                int bin = cch * BIN_CHUNK + ty + 16 * bi;
                float half_esq = 0.5f * es[bin];
                float s0 = acc[0][bi] - half_esq;
                float s1v = acc[1][bi] - half_esq;
                FUPD2(s0, bin, b1[0], i1[0], b2[0], i2[0]);
                FUPD2(s1v, bin, b1[1], i1[1], b2[1], i2[1]);
            }
        }

        #pragma unroll
        for (int k = 0; k < 2; ++k) {
            red_s[ty][k][tx]      = k ? b2[0] : b1[0];
            red_i[ty][k][tx]      = k ? i2[0] : i1[0];
            red_s[ty][k][tx + 16] = k ? b2[1] : b1[1];
            red_i[ty][k][tx + 16] = k ? i2[1] : i1[1];
        }
        __syncthreads();

        if (tid < TOK_PER_BLK) {
            float g1 = -1e30f, g2 = -1e30f; int gi1 = 0x7fffffff, gi2 = 0x7fffffff;
            #pragma unroll
            for (int j = 0; j < 16; ++j) {
                #pragma unroll
                for (int k = 0; k < 2; ++k) {
                    float s = red_s[j][k][tid]; int ii = red_i[j][k][tid];
                    FUPD2(s, ii, g1, gi1, g2, gi2);
                }
            }
            int bif;
            if (g1 - g2 <= FDELTA) {
                const float* rrow = r_lds[tid];
                double sc[2]; int id2[2] = { gi1, gi2 };
                for (int cc2 = 0; cc2 < 2; ++cc2) {
                    const float* ep = eb + (size_t)id2[cc2] * DD;
                    double acc2 = 0.0;
                    #pragma unroll 4
                    for (int d = 0; d < DD; ++d) {
                        double ev = (double)ep[d];
                        acc2 += ev * (2.0 * (double)rrow[d] - ev);
                    }
                    sc[cc2] = acc2;
                }
                bif = (sc[0] > sc[1] || (sc[0] == sc[1] && id2[0] < id2[1])) ? id2[0] : id2[1];
            } else {
                bif = gi1;
            }
            best_lds2[tid] = bif;
            out[OUTQ + (size_t)q * (BB * TT) + (size_t)b * TT + t0 + tid] = (float)bif;
        }
        __syncthreads();

        {
            const int tok  = tid >> 3;
            const int part = tid & 7;
            const int bin  = best_lds2[tok];
            const float* ep = eb + (size_t)bin * DD + part * 32;
            float* rp = &r_lds[tok][part * 32];
            #pragma unroll
            for (int dd = 0; dd < 32; ++dd) rp[dd] -= ep[dd];
        }
        __syncthreads();
    }

    {
        const int tl = tid & 31;
        const int d0 = (tid >> 5) * 32;
        const float* xp = x + (size_t)b * DD * TT + t0 + tl;
        float*       op = out + (size_t)b * DD * TT + t0 + tl;
        for (int dd = 0; dd < 32; ++dd) {
            int d = d0 + dd;
            op[(size_t)d * TT] = xp[(size_t)d * TT] - r_lds[tl][d];
        }
    }
}

extern "C" void kernel_launch(void* const* d_in, const int* in_sizes, int n_in,
                              void* d_out, int out_size, void* d_ws, size_t ws_size,
                              hipStream_t stream) {
    const float* x  = (const float*)d_in[0];
    const float* cb = (const float*)d_in[1];
    float* out = (float*)d_out;

    const size_t PKS_BYTES = (size_t)NQ * BINS * DD * 2;       // 4 MB fp16 pre-swizzled
    const size_t NEED = PKS_BYTES + (size_t)NQ * BINS * 4;     // + offset table

    if (ws_size >= NEED) {
        _Float16* pks = (_Float16*)d_ws;
        float* hoff = (float*)((char*)d_ws + PKS_BYTES);
        rvq_pack_h16<<<(NQ * BINS * 8) / 256, 256, 0, stream>>>(cb, pks);
        rvq_esq_off<<<NQ, 256, 0, stream>>>(cb, hoff);
        rvq_mfma11_kernel<<<512, 256, 0, stream>>>(x, cb, pks, hoff, out);
    } else {
        float* esq = (float*)d_ws;
        rvq_esq_kernel<<<NQ, 256, 0, stream>>>(cb, esq);
        rvq_main_kernel<<<(BB * TT) / TOK_PER_BLK, 256, 0, stream>>>(x, cb, esq, out);
    }
}

// Round 16
// 585.414 us; speedup vs baseline: 1.1161x; 1.0640x over previous
//
#include <hip/hip_runtime.h>

// Residual VQ forward: x [B=16, D=256, T=4096] fp32, codebooks [NQ=8, BINS=1024, D=256] fp32.
// d_out = quantized [B,D,T] fp32 ++ codes [NQ,B,T] as float.
// Round 16: depth-3 B-prefetch (Bx/By/Bz register sets, rotation unrolled x3, ~2
// chunk-computes of load cover) on the r14b barrier-free streaming skeleton. rl
// (residual low half, NOT used in the hot loop) moves to LDS to free 64 VGPRs for
// the third set. Numerics identical to r9-r15: fp16 1-term scoring, packed top-3,
// DELTA=4.0, fp64 refine3.

#define BB   16
#define DD   256
#define TT   4096
#define NQ   8
#define BINS 1024
#define DELTA 4.0f              // packed/scaled units (score scale = 16x, quantum <= 1.0)
#define SOFF  8192.0f           // shift making packed scores positive
#define OUTQ ((size_t)BB * DD * TT)

typedef _Float16 half8 __attribute__((ext_vector_type(8)));
typedef float    facc  __attribute__((ext_vector_type(4)));

#define MFMA16(A, B, C) __builtin_amdgcn_mfma_f32_16x16x32_f16((A), (B), (C), 0, 0, 0)

// ---------- pack kernel: fp32 codebook -> pre-swizzled fp16, 8 KB chunks ----------
// Chunk k = q*64 + ch covers bins ch*16..+15 of book q. Chunk = [8 planes][512 halves];
// plane s = k-slice; pos = g*128 + c*8 + j <-> (bin = ch*16 + c, d = s*32 + g*8 + j).
// Lane l of the consumer reads 16B at chunk_base + s*1024 + (l>>4)*256 + (l&15)*16.
__global__ __launch_bounds__(256)
void rvq_pack_h16(const float* __restrict__ cb, _Float16* __restrict__ pks) {
    int gid = blockIdx.x * 256 + threadIdx.x;       // (q, bin, s)
    int s   = gid & 7;
    int bin = (gid >> 3) & 1023;
    int q   = gid >> 13;
    const float* src = cb + ((size_t)(q * BINS + bin)) * DD + s * 32;
    int cc    = q * 64 + (bin >> 4);
    int c     = bin & 15;
    size_t base = (size_t)cc * 4096 + (size_t)s * 512 + c * 8;   // half units
    #pragma unroll
    for (int g = 0; g < 4; ++g) {
        float4 v0 = *(const float4*)(src + g * 8);
        float4 v1 = *(const float4*)(src + g * 8 + 4);
        float vv[8] = { v0.x, v0.y, v0.z, v0.w, v1.x, v1.y, v1.z, v1.w };
        half8 h8;
        #pragma unroll
        for (int j = 0; j < 8; ++j) h8[j] = (_Float16)vv[j];
        *(half8*)&pks[base + g * 128] = h8;
    }
}

// hoff = SOFF - 8*||e||^2   (packed score = 16*(r.e) + hoff, always positive)
__global__ __launch_bounds__(256)
void rvq_esq_off(const float* __restrict__ cb, float* __restrict__ hoff) {
    int q = blockIdx.x;
    const float* e = cb + (size_t)q * BINS * DD;
    for (int bin = threadIdx.x; bin < BINS; bin += 256) {
        const float4* row = (const float4*)(e + (size_t)bin * DD);
        float s = 0.f;
        #pragma unroll 8
        for (int i = 0; i < DD / 4; ++i) {
            float4 v = row[i];
            s += v.x * v.x + v.y * v.y + v.z * v.z + v.w * v.w;
        }
        hoff[q * BINS + bin] = SOFF - 8.0f * s;
    }
}

// ---------- main MFMA kernel: 512 blocks x 256 thr (4 waves), 32 tokens/wave ----------
__global__ __launch_bounds__(256, 2)
void rvq_mfma12_kernel(const float* __restrict__ x, const float* __restrict__ cb,
                       const _Float16* __restrict__ pks, const float* __restrict__ hoff,
                       float* __restrict__ out)
{
    __shared__ float esq_lds[BINS];                      // 4 KB: offsets, current stage
    __shared__ half8 rl_lds[2][8][4][64];                // 64 KB: residual low halves
    __shared__ unsigned short best_lds[4][32];
    __shared__ unsigned short hist_lds[4][NQ][32];

    const int tid = threadIdx.x;
    const int w   = tid >> 6;
    const int l   = tid & 63;
    const int c   = l & 15;
    const int g   = l >> 4;

    const int blk = blockIdx.x;        // 512 blocks
    const int b   = blk >> 5;          // 32 blocks per batch element
    const int t0  = (blk & 31) * 128;
    const int tw  = t0 + w * 32;

    // per-lane source base inside each 8 KB chunk
    const char* pkbase = (const char*)pks + ((l >> 4) * 256 + (l & 15) * 16);

    // ---- A init: 16*residual = 16*x, split to fp16 (rh regs, rl -> LDS) ----
    half8 rh[2][8];
    {
        const float* xb = x + (size_t)b * DD * TT;
        #pragma unroll
        for (int s = 0; s < 8; ++s) {
            #pragma unroll
            for (int j = 0; j < 8; ++j) {
                int d = s * 32 + g * 8 + j;
                #pragma unroll
                for (int m = 0; m < 2; ++m) {
                    int t = tw + m * 16 + c;
                    float v = 16.0f * xb[(size_t)d * TT + t];
                    _Float16 h = (_Float16)v;
                    rh[m][s][j] = h;
                    // rl element j assembled below via LDS write (per (m,s) vector)
                }
            }
        }
        // build + store rl vectors (second pass keeps rh path simple)
        #pragma unroll
        for (int s = 0; s < 8; ++s) {
            #pragma unroll
            for (int m = 0; m < 2; ++m) {
                int t = tw + m * 16 + c;
                half8 rlv;
                #pragma unroll
                for (int j = 0; j < 8; ++j) {
                    int d = s * 32 + g * 8 + j;
                    float v = 16.0f * xb[(size_t)d * TT + t];
                    rlv[j] = (_Float16)(v - (float)rh[m][s][j]);
                }
                rl_lds[m][s][w][l] = rlv;
            }
        }
    }
    // stage offset table for stage 0 (256 threads x 4 floats)
    {
        float4 v = *(const float4*)(hoff + tid * 4);
        *(float4*)&esq_lds[tid * 4] = v;
    }
    __syncthreads();

    // packed top-3 fold state: slot (fm, fj) = token fm*16 + 4*g + fj
    float p1[2][4], p2[2][4], p3[2][4];

    // B-fragment register sets (3-deep rotation, statically named)
    half8 Bx[8], By[8], Bz[8];

#define LOADB(BSET, K) do {                                                  \
    const char* _src = pkbase + (size_t)(K) * 8192;                          \
    _Pragma("unroll")                                                        \
    for (int _s = 0; _s < 8; ++_s)                                           \
        BSET[_s] = *(const half8*)(_src + _s * 1024);                        \
} while (0)

#define COMPUTE(BSET, CH) do {                                               \
    facc _a0 = {0.f,0.f,0.f,0.f}, _a1 = {0.f,0.f,0.f,0.f};                   \
    _Pragma("unroll")                                                        \
    for (int _s = 0; _s < 8; ++_s) {                                         \
        _a0 = MFMA16(rh[0][_s], BSET[_s], _a0);                              \
        _a1 = MFMA16(rh[1][_s], BSET[_s], _a1);                              \
    }                                                                        \
    const float _q0 = esq_lds[(CH) * 16 + c];                                \
    const unsigned _idx0 = 1023u - (unsigned)((CH) * 16 + c);                \
    _Pragma("unroll")                                                        \
    for (int _fm = 0; _fm < 2; ++_fm) {                                      \
        _Pragma("unroll")                                                    \
        for (int _fj = 0; _fj < 4; ++_fj) {                                  \
            float _sv = (_fm ? _a1[_fj] : _a0[_fj]) + _q0;                   \
            float _v = __builtin_bit_cast(float,                            \
                         (__builtin_bit_cast(unsigned, _sv) & ~1023u) | _idx0); \
            float _o1 = p1[_fm][_fj], _o2 = p2[_fm][_fj], _o3 = p3[_fm][_fj]; \
            p1[_fm][_fj] = fmaxf(_o1, _v);                                   \
            p2[_fm][_fj] = __builtin_amdgcn_fmed3f(_v, _o1, _o2);            \
            p3[_fm][_fj] = __builtin_amdgcn_fmed3f(_v, _o2, _o3);            \
        }                                                                    \
    }                                                                        \
} while (0)

    // rare: exact fp32 residual chain + fp64 re-score of the three candidates
    auto refine3 = [&](int tkl, int qq, int c1, int c2, int c3) -> int {
        int t = tw + tkl;
        double pa = 0.0, pb = 0.0, pc = 0.0;
        const float* e1p = cb + (size_t)(qq * BINS + c1) * DD;
        const float* e2p = cb + (size_t)(qq * BINS + c2) * DD;
        const float* e3p = cb + (size_t)(qq * BINS + c3) * DD;
        #pragma unroll
        for (int dd = 0; dd < 4; ++dd) {
            int d = l * 4 + dd;
            float rv = x[((size_t)b * DD + d) * TT + t];
            for (int k = 0; k < qq; ++k) {
                int hb = hist_lds[w][k][tkl];
                rv -= cb[(size_t)(k * BINS + hb) * DD + d];
            }
            float e1v = e1p[d], e2v = e2p[d], e3v = e3p[d];
            pa += (double)e1v * (2.0 * (double)rv - (double)e1v);
            pb += (double)e2v * (2.0 * (double)rv - (double)e2v);
            pc += (double)e3v * (2.0 * (double)rv - (double)e3v);
        }
        #pragma unroll
        for (int mk = 1; mk < 64; mk <<= 1) {
            pa += __shfl_xor(pa, mk);
            pb += __shfl_xor(pb, mk);
            pc += __shfl_xor(pc, mk);
        }
        int wbin = c1; double pw = pa;
        if (pb > pw || (pb == pw && c2 < wbin)) { pw = pb; wbin = c2; }
        if (pc > pw || (pc == pw && c3 < wbin)) { pw = pc; wbin = c3; }
        return wbin;
    };

    auto stage_end = [&](int qq) {
        int  bch[2][4], cn2[2][4], cn3[2][4];
        bool gate[2][4];
        #pragma unroll
        for (int fm = 0; fm < 2; ++fm) {
            #pragma unroll
            for (int fj = 0; fj < 4; ++fj) {
                float a1 = p1[fm][fj], a2 = p2[fm][fj], a3 = p3[fm][fj];
                #pragma unroll
                for (int mk = 1; mk < 16; mk <<= 1) {
                    float b1 = __shfl_xor(a1, mk);
                    float b2 = __shfl_xor(a2, mk);
                    float b3 = __shfl_xor(a3, mk);
                    float lo1 = fminf(a1, b1);
                    float m22 = fmaxf(a2, b2);
                    float r1  = fmaxf(a1, b1);
                    float r2  = fmaxf(lo1, m22);
                    float r3  = fmaxf(fminf(lo1, m22), fmaxf(fminf(a2, b2), fmaxf(a3, b3)));
                    a1 = r1; a2 = r2; a3 = r3;
                }
                bch[fm][fj] = 1023 - (int)(__builtin_bit_cast(unsigned, a1) & 1023u);
                cn2[fm][fj] = 1023 - (int)(__builtin_bit_cast(unsigned, a2) & 1023u);
                cn3[fm][fj] = 1023 - (int)(__builtin_bit_cast(unsigned, a3) & 1023u);
                gate[fm][fj] = (a1 - a2 <= DELTA);
            }
        }
        bool anyg = gate[0][0] | gate[0][1] | gate[0][2] | gate[0][3]
                  | gate[1][0] | gate[1][1] | gate[1][2] | gate[1][3];
        if (__any(anyg)) {
            #pragma unroll
            for (int fm = 0; fm < 2; ++fm) {
                #pragma unroll
                for (int fj = 0; fj < 4; ++fj) {
                    unsigned long long nm = __ballot(gate[fm][fj]);
                    if (nm) {
                        for (int g2 = 0; g2 < 4; ++g2) {
                            if ((nm >> (g2 * 16)) & 1ull) {
                                int c1 = __shfl(bch[fm][fj], g2 * 16);
                                int c2 = __shfl(cn2[fm][fj], g2 * 16);
                                int c3 = __shfl(cn3[fm][fj], g2 * 16);
                                int tkl = fm * 16 + g2 * 4 + fj;
                                int wb = refine3(tkl, qq, c1, c2, c3);
                                if (g == g2) bch[fm][fj] = wb;
                            }
                        }
                    }
                }
            }
        }

        // writes: codes + per-wave best/history
        if (c == 0) {
            #pragma unroll
            for (int fm = 0; fm < 2; ++fm)
                #pragma unroll
                for (int fj = 0; fj < 4; ++fj) {
                    int tkl = fm * 16 + g * 4 + fj;
                    best_lds[w][tkl] = (unsigned short)bch[fm][fj];
                    hist_lds[w][qq][tkl] = (unsigned short)bch[fm][fj];
                    out[OUTQ + ((size_t)qq * BB + b) * TT + tw + tkl] = (float)bch[fm][fj];
                }
        }

        // residual update from EXACT fp32 codebook row: 16r -= 16*e[best], re-split fp16
        #pragma unroll
        for (int m = 0; m < 2; ++m) {
            int bin = best_lds[w][m * 16 + c];
            const float* ep = cb + (size_t)(qq * BINS + bin) * DD + g * 8;
            #pragma unroll
            for (int s = 0; s < 8; ++s) {
                float4 e0 = *(const float4*)(ep + s * 32);
                float4 e1 = *(const float4*)(ep + s * 32 + 4);
                float ev[8] = { e0.x, e0.y, e0.z, e0.w, e1.x, e1.y, e1.z, e1.w };
                half8 rlv = rl_lds[m][s][w][l];
                half8 nrl;
                #pragma unroll
                for (int j = 0; j < 8; ++j) {
                    float rv = (float)rh[m][s][j] + (float)rlv[j];
                    float nr = rv - 16.0f * ev[j];
                    _Float16 nh = (_Float16)nr;
                    rh[m][s][j] = nh;
                    nrl[j] = (_Float16)(nr - (float)nh);
                }
                rl_lds[m][s][w][l] = nrl;
            }
        }
    };

    // ---- main loop: 8 stages x 64 chunks (16 bins); wave-private, depth-3 prefetch ----
    #pragma unroll 1
    for (int q = 0; q < NQ; ++q) {
        #pragma unroll
        for (int fm = 0; fm < 2; ++fm)
            #pragma unroll
            for (int fj = 0; fj < 4; ++fj) {
                p1[fm][fj] = 0.f; p2[fm][fj] = 0.f; p3[fm][fj] = 0.f;
            }
        const int base = q * 64;
        LOADB(Bx, base + 0);
        LOADB(By, base + 1);
        LOADB(Bz, base + 2);
        #pragma unroll 1
        for (int pp = 0; pp < 21; ++pp) {
            const int ch = 3 * pp;
            COMPUTE(Bx, ch);
            LOADB(Bx, base + ch + 3);                    // ch+3 <= 63 always
            COMPUTE(By, ch + 1);
            if (ch + 4 < 64) LOADB(By, base + ch + 4);
            COMPUTE(Bz, ch + 2);
            if (ch + 5 < 64) LOADB(Bz, base + ch + 5);
        }
        COMPUTE(Bx, 63);                                 // chunk 63 lives in Bx
        stage_end(q);
        __syncthreads();          // all waves done with this stage's esq
        if (q + 1 < NQ) {
            float4 v = *(const float4*)(hoff + (q + 1) * BINS + tid * 4);
            *(float4*)&esq_lds[tid * 4] = v;
        }
        __syncthreads();          // offsets published before next stage reads them
    }

    // ---- final: quantized = x - residual (m-inner: 128B line back-to-back) ----
    {
        const float* xb = x + (size_t)b * DD * TT;
        float* ob = out + (size_t)b * DD * TT;
        #pragma unroll
        for (int s = 0; s < 8; ++s) {
            half8 rl0 = rl_lds[0][s][w][l];
            half8 rl1 = rl_lds[1][s][w][l];
            #pragma unroll
            for (int j = 0; j < 8; ++j) {
                int d = s * 32 + g * 8 + j;
                #pragma unroll
                for (int m = 0; m < 2; ++m) {
                    int t = tw + m * 16 + c;
                    float rlv = (float)(m ? rl1[j] : rl0[j]);
                    float rv = ((float)rh[m][s][j] + rlv) * 0.0625f;
                    ob[(size_t)d * TT + t] = xb[(size_t)d * TT + t] - rv;
                }
            }
        }
    }
}

// ================= fallback fp32 path (round-2, known-good) =================
#define TOK_PER_BLK 32
#define BIN_CHUNK   128
#define KC          32
#define EPAD        36
#define RPAD        260
#define FDELTA      0.0078125f

#define FUPD2(S, BIN, B1, I1, B2, I2)                                        \
    if ((S) > (B2) || ((S) == (B2) && (BIN) < (I2))) {                      \
        if ((S) > (B1) || ((S) == (B1) && (BIN) < (I1))) {                  \
            B2 = B1; I2 = I1; B1 = (S); I1 = (BIN);                         \
        } else { B2 = (S); I2 = (BIN); }                                    \
    }

__global__ __launch_bounds__(256, 2)
void rvq_esq_kernel(const float* __restrict__ cb, float* __restrict__ esq) {
    int q = blockIdx.x;
    const float* e = cb + (size_t)q * BINS * DD;
    for (int bin = threadIdx.x; bin < BINS; bin += 256) {
        const float4* row = (const float4*)(e + (size_t)bin * DD);
        float s = 0.f;
        #pragma unroll 8
        for (int i = 0; i < DD / 4; ++i) {
            float4 v = row[i];
            s += v.x * v.x + v.y * v.y + v.z * v.z + v.w * v.w;
        }
        esq[q * BINS + bin] = s;
    }
}

__global__ __launch_bounds__(256, 2)
void rvq_main_kernel(const float* __restrict__ x, const float* __restrict__ cb,
                     const float* __restrict__ esq, float* __restrict__ out) {
    __shared__ float r_lds[TOK_PER_BLK][RPAD];
    __shared__ float e_lds[BIN_CHUNK][EPAD];
    __shared__ float red_s[16][2][TOK_PER_BLK];
    __shared__ int   red_i[16][2][TOK_PER_BLK];
    __shared__ int   best_lds2[TOK_PER_BLK];

    const int tid = threadIdx.x;
    const int blk = blockIdx.x;
    const int b   = blk >> 7;
    const int t0  = (blk & 127) * TOK_PER_BLK;

    {
        const int tl = tid & 31;
        const int d0 = (tid >> 5) * 32;
        const float* xp = x + (size_t)b * DD * TT + t0 + tl;
        for (int dd = 0; dd < 32; ++dd) {
            int d = d0 + dd;
            r_lds[tl][d] = xp[(size_t)d * TT];
        }
    }
    __syncthreads();

    const int ty = tid >> 4;
    const int tx = tid & 15;

    for (int q = 0; q < NQ; ++q) {
        const float* eb = cb + (size_t)q * BINS * DD;
        const float* es = esq + q * BINS;
        float b1[2] = {-1e30f, -1e30f}, b2[2] = {-1e30f, -1e30f};
        int   i1[2] = {0x7fffffff, 0x7fffffff}, i2[2] = {0x7fffffff, 0x7fffffff};

        for (int cch = 0; cch < BINS / BIN_CHUNK; ++cch) {
            float acc[2][8];
            #pragma unroll
            for (int i = 0; i < 2; ++i)
                #pragma unroll
                for (int j = 0; j < 8; ++j) acc[i][j] = 0.f;

            for (int kc = 0; kc < DD / KC; ++kc) {
                __syncthreads();
                {
                    const int col  = tid & 7;
                    const int row0 = tid >> 3;
                    const float* src = eb + (size_t)(cch * BIN_CHUNK) * DD + kc * KC;
                    #pragma unroll
                    for (int rr = 0; rr < 4; ++rr) {
                        int row = row0 + rr * 32;
                        float4 v = *(const float4*)(src + (size_t)row * DD + col * 4);
                        *(float4*)&e_lds[row][col * 4] = v;
                    }
                }
                __syncthreads();
                #pragma unroll
                for (int k4 = 0; k4 < KC / 4; ++k4) {
                    float4 r0 = *(const float4*)&r_lds[tx][kc * KC + k4 * 4];
                    float4 r1 = *(const float4*)&r_lds[tx + 16][kc * KC + k4 * 4];
                    #pragma unroll
                    for (int bi = 0; bi < 8; ++bi) {
                        float4 e4 = *(const float4*)&e_lds[ty + 16 * bi][k4 * 4];
                        acc[0][bi] += r0.x * e4.x + r0.y * e4.y + r0.z * e4.z + r0.w * e4.w;
                        acc[1][bi] += r1.x * e4.x + r1.y * e4.y + r1.z * e4.z + r1.w * e4.w;
                    }
                }
            }
            #pragma unroll
            for (int bi = 0; bi < 8; ++bi) {
                int bin = cch * BIN_CHUNK + ty + 16 * bi;
                float half_esq = 0.5f * es[bin];
                float s0 = acc[0][bi] - half_esq;
                float s1v = acc[1][bi] - half_esq;
                FUPD2(s0, bin, b1[0], i1[0], b2[0], i2[0]);
                FUPD2(s1v, bin, b1[1], i1[1], b2[1], i2[1]);
            }
        }

        #pragma unroll
        for (int k = 0; k < 2; ++k) {
            red_s[ty][k][tx]      = k ? b2[0] : b1[0];
            red_i[ty][k][tx]      = k ? i2[0] : i1[0];
            red_s[ty][k][tx + 16] = k ? b2[1] : b1[1];
            red_i[ty][k][tx + 16] = k ? i2[1] : i1[1];
        }
        __syncthreads();

        if (tid < TOK_PER_BLK) {
            float g1 = -1e30f, g2 = -1e30f; int gi1 = 0x7fffffff, gi2 = 0x7fffffff;
            #pragma unroll
            for (int j = 0; j < 16; ++j) {
                #pragma unroll
                for (int k = 0; k < 2; ++k) {
                    float s = red_s[j][k][tid]; int ii = red_i[j][k][tid];
                    FUPD2(s, ii, g1, gi1, g2, gi2);
                }
            }
            int bif;
            if (g1 - g2 <= FDELTA) {
                const float* rrow = r_lds[tid];
                double sc[2]; int id2[2] = { gi1, gi2 };
                for (int cc2 = 0; cc2 < 2; ++cc2) {
                    const float* ep = eb + (size_t)id2[cc2] * DD;
                    double acc2 = 0.0;
                    #pragma unroll 4
                    for (int d = 0; d < DD; ++d) {
                        double ev = (double)ep[d];
                        acc2 += ev * (2.0 * (double)rrow[d] - ev);
                    }
                    sc[cc2] = acc2;
                }
                bif = (sc[0] > sc[1] || (sc[0] == sc[1] && id2[0] < id2[1])) ? id2[0] : id2[1];
            } else {
                bif = gi1;
            }
            best_lds2[tid] = bif;
            out[OUTQ + (size_t)q * (BB * TT) + (size_t)b * TT + t0 + tid] = (float)bif;
        }
        __syncthreads();

        {
            const int tok  = tid >> 3;
            const int part = tid & 7;
            const int bin  = best_lds2[tok];
            const float* ep = eb + (size_t)bin * DD + part * 32;
            float* rp = &r_lds[tok][part * 32];
            #pragma unroll
            for (int dd = 0; dd < 32; ++dd) rp[dd] -= ep[dd];
        }
        __syncthreads();
    }

    {
        const int tl = tid & 31;
        const int d0 = (tid >> 5) * 32;
        const float* xp = x + (size_t)b * DD * TT + t0 + tl;
        float*       op = out + (size_t)b * DD * TT + t0 + tl;
        for (int dd = 0; dd < 32; ++dd) {
            int d = d0 + dd;
            op[(size_t)d * TT] = xp[(size_t)d * TT] - r_lds[tl][d];
        }
    }
}

extern "C" void kernel_launch(void* const* d_in, const int* in_sizes, int n_in,
                              void* d_out, int out_size, void* d_ws, size_t ws_size,
                              hipStream_t stream) {
    const float* x  = (const float*)d_in[0];
    const float* cb = (const float*)d_in[1];
    float* out = (float*)d_out;

    const size_t PKS_BYTES = (size_t)NQ * BINS * DD * 2;       // 4 MB fp16 pre-swizzled
    const size_t NEED = PKS_BYTES + (size_t)NQ * BINS * 4;     // + offset table

    if (ws_size >= NEED) {
        _Float16* pks = (_Float16*)d_ws;
        float* hoff = (float*)((char*)d_ws + PKS_BYTES);
        rvq_pack_h16<<<(NQ * BINS * 8) / 256, 256, 0, stream>>>(cb, pks);
        rvq_esq_off<<<NQ, 256, 0, stream>>>(cb, hoff);
        rvq_mfma12_kernel<<<512, 256, 0, stream>>>(x, cb, pks, hoff, out);
    } else {
        float* esq = (float*)d_ws;
        rvq_esq_kernel<<<NQ, 256, 0, stream>>>(cb, esq);
        rvq_main_kernel<<<(BB * TT) / TOK_PER_BLK, 256, 0, stream>>>(x, cb, esq, out);
    }
}